// Round 2
// baseline (146.562 us; speedup 1.0000x reference)
//
#include <hip/hip_runtime.h>
#include <math.h>

#define NQ 12
#define DIM 4096
#define KS 6
#define BB 256
#define SEQ 128
#define DEMB 512

// v3: 1024 threads, 4 amps/thread; intra-wave layout trips done with
// __shfl_xor reg<->lane bit swaps (no LDS, no lgkmcnt(0) drains).
// Only the 2 cross-wave trips (D->E, ring scatter) use LDS: 2 barriers/step.
// R1 counters: dur 57us, VALUBusy 44%, bank-conflict 2.36M -> LDS-trip
// latency chains are the residual stall; this removes 4 of 6 trips.
//
// Layouts (j = 12-bit state index, wire w <-> bit 11-w):
//  L_A: r=j[1:0]   lane=j[7:2]            wave=j[11:8]
//  L_B: r=j[3:2]   lane={j[7:4],j[1:0]}   wave=j[11:8]
//  L_C: r=j[5:4]   lane={j[7:6],j[3:0]}   wave=j[11:8]
//  L_D: r=j[7:6]   lane=j[5:0]            wave=j[11:8]
//  L_E: r=j[9:8]   lane={j[11:10],j[3:0]} wave=j[7:4]
//  L_F: r=j[11:10] lane={j[9:8],j[3:0]}   wave=j[7:4]
// A->B: swap (r0,l0)(r1,l1); B->C: (r0,l2)(r1,l3); C->D: (r0,l4)(r1,l5)
// E->F: (r0,l4)(r1,l5).  D->E cross-wave (buf0, B1); ring F->A' (buf2, B2).
// Expvals PRE-ring in L_F via prefix-XOR parity strings (verified R1).

#define RG(P, W) { \
    float4 c0 = *(const float4*)&s_u[k][W][0]; \
    float4 c1 = *(const float4*)&s_u[k][W][4]; \
    float u00r=c0.x,u00i=c0.y,u01r=c0.z,u01i=c0.w; \
    float u10r=c1.x,u10i=c1.y,u11r=c1.z,u11i=c1.w; \
    _Pragma("unroll") \
    for (int r0 = 0; r0 < 4; ++r0) if (!(r0 & (1 << (P)))) { \
        int r1 = r0 | (1 << (P)); \
        float2 A = a[r0], Bv = a[r1]; \
        a[r0].x = u00r*A.x - u00i*A.y + u01r*Bv.x - u01i*Bv.y; \
        a[r0].y = u00r*A.y + u00i*A.x + u01r*Bv.y + u01i*Bv.x; \
        a[r1].x = u10r*A.x - u10i*A.y + u11r*Bv.x - u11i*Bv.y; \
        a[r1].y = u10r*A.y + u10i*A.x + u11r*Bv.y + u11i*Bv.x; \
    } }

// Swap reg-bit (lo/hi pair) with lane-bit M: element (r=1,laneM=0)
// exchanges with (r=0,laneM=1); others stay. 2 shuffles + 4 cndmask.
#define SWAPB(lo, hi, M) { \
    float tx_ = (lane & M) ? lo.x : hi.x; \
    float ty_ = (lane & M) ? lo.y : hi.y; \
    tx_ = __shfl_xor(tx_, M, 64); \
    ty_ = __shfl_xor(ty_, M, 64); \
    if (lane & M) { lo.x = tx_; lo.y = ty_; } \
    else          { hi.x = tx_; hi.y = ty_; } \
}

#define BF_PLAIN(v, m) { float p_ = __shfl_xor(v, m, 64); v = v + p_; }
#define BF_SIGN(v, m)  { float p_ = __shfl_xor(v, m, 64); float d_ = v - p_; \
                         v = (lane & m) ? -d_ : d_; }

__device__ __forceinline__ int swz14(int x) { return x ^ ((x >> 4) & 14); }

__global__ __launch_bounds__(1024) void fused_kernel(
    const int* __restrict__ ids, const int* __restrict__ mask,
    const float* __restrict__ emb, const float* __restrict__ pw,
    const float* __restrict__ pb, const float* __restrict__ theta,
    const float* __restrict__ hw, const float* __restrict__ hb,
    float* __restrict__ readouts, float* __restrict__ logits,
    float* __restrict__ last)
{
    __shared__ __align__(16) float2 buf0[DIM];   // 32 KB (trip D->E / enc partials)
    __shared__ __align__(16) float2 buf2[DIM];   // 32 KB (ring scatter / enc ids)
    __shared__ __align__(16) float  s_u[KS][NQ][8];
    __shared__ float  s_red[16][NQ];
    __shared__ float  s_msum[8];
    __shared__ float  s_wred[2][NQ];
    __shared__ float  s_x[NQ];
    __shared__ float  s_hw[8 * NQ];
    __shared__ float  s_hb[8];

    int b = blockIdx.x;
    int tid = threadIdx.x;
    int lane = tid & 63, wave = tid >> 6;     // wave 0..15

    // ---------------- encoder ----------------
    int*   s_ids = (int*)buf2;
    float* s_m   = (float*)buf2 + SEQ;
    float4* s_part = (float4*)buf0;           // [8][128]

    if (tid < SEQ) {
        s_ids[tid] = ids[b * SEQ + tid];
        s_m[tid]   = (float)mask[b * SEQ + tid];
    }
    if (tid >= 256 && tid < 256 + 8 * NQ) s_hw[tid - 256] = hw[tid - 256];
    if (tid >= 384 && tid < 392)          s_hb[tid - 384] = hb[tid - 384];
    __syncthreads();

    {
        int g = tid >> 7, e = tid & 127;      // g 0..7
        float4 acc = make_float4(0.f, 0.f, 0.f, 0.f);
        float msum = 0.f;
        #pragma unroll 4
        for (int s = g; s < SEQ; s += 8) {
            float m = s_m[s];
            float4 v = ((const float4*)emb)[(size_t)s_ids[s] * 128 + e];
            acc.x = fmaf(m, v.x, acc.x);
            acc.y = fmaf(m, v.y, acc.y);
            acc.z = fmaf(m, v.z, acc.z);
            acc.w = fmaf(m, v.w, acc.w);
            msum += m;
        }
        __syncthreads();   // all s_ids/s_m reads complete
        s_part[g * 128 + e] = acc;
        if (e == 0) s_msum[g] = msum;
    }
    __syncthreads();

    if (tid < 128) {
        float tm = s_msum[0] + s_msum[1] + s_msum[2] + s_msum[3]
                 + s_msum[4] + s_msum[5] + s_msum[6] + s_msum[7];
        tm = fmaxf(tm, 1.f);
        float inv = 1.f / tm;
        float4 p = make_float4(0.f, 0.f, 0.f, 0.f);
        #pragma unroll
        for (int g = 0; g < 8; ++g) {
            float4 pg = s_part[g * 128 + tid];
            p.x += pg.x; p.y += pg.y; p.z += pg.z; p.w += pg.w;
        }
        p.x *= inv; p.y *= inv; p.z *= inv; p.w *= inv;
        float z[NQ];
        #pragma unroll
        for (int i = 0; i < NQ; ++i) {
            float4 w4 = ((const float4*)pw)[i * 128 + tid];
            z[i] = p.x * w4.x + p.y * w4.y + p.z * w4.z + p.w * w4.w;
        }
        #pragma unroll
        for (int i = 0; i < NQ; ++i) {
            #pragma unroll
            for (int off = 32; off > 0; off >>= 1)
                z[i] += __shfl_xor(z[i], off, 64);
        }
        if ((tid & 63) == 0) {
            int w = tid >> 6;
            #pragma unroll
            for (int i = 0; i < NQ; ++i) s_wred[w][i] = z[i];
        }
    }
    __syncthreads();
    if (tid < NQ) {
        float d = pb[tid] + s_wred[0][tid] + s_wred[1][tid];
        s_x[tid] = tanhf(d) * 3.14159274101257324f;
    }
    __syncthreads();

    // ------ gate matrices: U = Rot(phi,te,om) @ RY(x), SU(2)-compressed ---
    // U has only 4 independent reals: E0..E3; slots = [E0,E1,E2,E3,-E2,E3,E0,-E1]
    if (tid < KS * NQ * 4) {
        int k = tid / 48;
        int rem = tid - k * 48;
        int w = rem >> 2, q = rem & 3;
        float ang = s_x[w];
        float cy = cosf(0.5f * ang), sy = sinf(0.5f * ang);
        const float* th = theta + (k * NQ + w) * 3;
        float phi = th[0], te = th[1], om = th[2];
        float ct = cosf(0.5f * te), st = sinf(0.5f * te);
        float a1 = -0.5f * (phi + om);
        float a2 =  0.5f * (phi - om);
        float ar =  cosf(a1) * ct, ai =  sinf(a1) * ct;   // R00 = conj(R11)
        float br = -cosf(a2) * st, bi = -sinf(a2) * st;   // R01 = -conj(R10)
        float x1 = (q & 1) ? ai : ar;
        float x2 = (q & 1) ? bi : br;
        float E  = (q & 2) ? (x2 * cy - x1 * sy) : (x1 * cy + x2 * sy);
        s_u[k][w][q] = E;
        s_u[k][w][(q & 2) ? q + 2 : q + 6] = (q == 1 || q == 2) ? -E : E;
    }

    // ---------------- constant addresses (cross-wave trips only) --------
    int T4 = tid << 2;                 // L_A base logical index (4 amps)
    int bA4 = swz14(T4) >> 1;          // float4 idx; partner at bA4^1
    int aD[4], aE[4], idxP[4];
    #pragma unroll
    for (int r = 0; r < 4; ++r) {
        aD[r] = swz14((wave << 8) | (r << 6) | lane);
        aE[r] = swz14(((lane >> 4) << 10) | (r << 8) | (wave << 4) | (lane & 15));
        int jF = (r << 10) | ((lane >> 4) << 8) | (wave << 4) | (lane & 15);
        // ring CNOT permutation (prefix-XOR), harness-verified
        int b0 = (jF >> 11) & 1;
        int pref = b0, outv = 0;
        for (int w = 1; w < NQ; ++w) {
            pref ^= (jF >> (11 - w)) & 1;
            outv |= pref << (11 - w);
        }
        outv |= (b0 ^ pref) << 11;
        idxP[r] = swz14(outv);
    }
    // wave-bit (j[7:4]) sign parities for expvals
    int s3v   = (wave >> 3) & 1;               // j[7]   (wire 4)
    int s32v  = s3v ^ ((wave >> 2) & 1);       // j[7:6]
    int s321v = s32v ^ ((wave >> 1) & 1);      // j[7:5]
    int sallv = s321v ^ (wave & 1);            // j[7:4]

    float2 a[4];
    #pragma unroll
    for (int r = 0; r < 4; ++r) a[r] = make_float2(0.f, 0.f);
    if (tid == 0) a[0].x = 1.f;     // |0...0>: j=0 -> wave0,lane0,r0
    __syncthreads();   // s_u ready, enc buf reads done

    // ---------------- K steps ----------------
    for (int k = 0; k < KS; ++k) {
        // phase A (L_A): wires 11,10
        RG(0, 11) RG(1, 10)

        // trip 1 (shuffle): swap (r0<->l0 [j0<->j2]), (r1<->l1 [j1<->j3])
        SWAPB(a[0], a[1], 1) SWAPB(a[2], a[3], 1)
        SWAPB(a[0], a[2], 2) SWAPB(a[1], a[3], 2)

        // phase B (L_B): wires 9,8
        RG(0, 9) RG(1, 8)

        // trip 2 (shuffle): swap (r0<->l2 [j2<->j4]), (r1<->l3 [j3<->j5])
        SWAPB(a[0], a[1], 4) SWAPB(a[2], a[3], 4)
        SWAPB(a[0], a[2], 8) SWAPB(a[1], a[3], 8)

        // phase C (L_C): wires 7,6
        RG(0, 7) RG(1, 6)

        // trip 3 (shuffle): swap (r0<->l4 [j4<->j6]), (r1<->l5 [j5<->j7])
        SWAPB(a[0], a[1], 16) SWAPB(a[2], a[3], 16)
        SWAPB(a[0], a[2], 32) SWAPB(a[1], a[3], 32)

        // phase D (L_D): wires 5,4
        RG(0, 5) RG(1, 4)

        // trip 4 (cross-wave): dump L_D -> barrier -> gather L_E
        #pragma unroll
        for (int r = 0; r < 4; ++r) buf0[aD[r]] = a[r];
        __syncthreads();                                   // B1
        #pragma unroll
        for (int r = 0; r < 4; ++r) a[r] = buf0[aE[r]];

        // phase E (L_E): wires 3,2
        RG(0, 3) RG(1, 2)

        // trip 5 (shuffle): swap (r0<->l4 [j8<->j10]), (r1<->l5 [j9<->j11])
        SWAPB(a[0], a[1], 16) SWAPB(a[2], a[3], 16)
        SWAPB(a[0], a[2], 32) SWAPB(a[1], a[3], 32)

        // phase F (L_F): wires 1,0
        RG(0, 1) RG(1, 0)

        // ring scatter FIRST (drains while expvals shuffle), into buf2
        #pragma unroll
        for (int r = 0; r < 4; ++r) buf2[idxP[r]] = a[r];

        // expvals PRE-ring in L_F (verified R1): in-thread over r=j[11:10];
        // lane signs l5..l0 = j9,j8,j3..j0; wave signs j[7:4] at s_red write.
        {
            float p0 = a[0].x*a[0].x + a[0].y*a[0].y;
            float p1 = a[1].x*a[1].x + a[1].y*a[1].y;
            float p2 = a[2].x*a[2].x + a[2].y*a[2].y;
            float p3 = a[3].x*a[3].x + a[3].y*a[3].y;
            float T1v = (p0 + p3) - (p1 + p2);   // (-1)^(j11^j10)
            float T0v = (p0 + p2) - (p1 + p3);   // (-1)^(j10)

            float v1 = T1v;                       // wire 1: parity j[11:10]
            BF_PLAIN(v1,32) BF_PLAIN(v1,16) BF_PLAIN(v1,8)
            BF_PLAIN(v1,4)  BF_PLAIN(v1,2)  BF_PLAIN(v1,1)

            float c = T1v;
            BF_SIGN(c,32);                        // +j[9]
            float w2v = c; BF_PLAIN(w2v,16) BF_PLAIN(w2v,8) BF_PLAIN(w2v,4)
                           BF_PLAIN(w2v,2)  BF_PLAIN(w2v,1)
            BF_SIGN(c,16);                        // +j[8]
            float w3v = c; BF_PLAIN(w3v,8) BF_PLAIN(w3v,4)
                           BF_PLAIN(w3v,2) BF_PLAIN(w3v,1)
            BF_SIGN(c,8);                         // +j[3]
            float w8v = c; BF_PLAIN(w8v,4) BF_PLAIN(w8v,2) BF_PLAIN(w8v,1)
            BF_SIGN(c,4);                         // +j[2]
            float w9v = c; BF_PLAIN(w9v,2) BF_PLAIN(w9v,1)
            BF_SIGN(c,2);                         // +j[1]
            float w10v = c; BF_PLAIN(w10v,1)
            BF_SIGN(c,1);                         // +j[0]

            float q0 = T0v;                       // wire 0: parity j[10:0]
            BF_SIGN(q0,32) BF_SIGN(q0,16) BF_SIGN(q0,8)
            BF_SIGN(q0,4)  BF_SIGN(q0,2)  BF_SIGN(q0,1)

            if (lane == 0) {
                float* sr = s_red[wave];
                sr[0]  = sallv ? -q0   : q0;
                sr[1]  = v1;
                sr[2]  = w2v;
                sr[3]  = w3v;
                sr[4]  = s3v   ? -w3v  : w3v;
                sr[5]  = s32v  ? -w3v  : w3v;
                sr[6]  = s321v ? -w3v  : w3v;
                sr[7]  = sallv ? -w3v  : w3v;
                sr[8]  = sallv ? -w8v  : w8v;
                sr[9]  = sallv ? -w9v  : w9v;
                sr[10] = sallv ? -w10v : w10v;
                sr[11] = sallv ? -c    : c;
            }
        }

        __syncthreads();                                   // B2
        #pragma unroll
        for (int i = 0; i < 2; ++i) {
            float4 v = ((float4*)buf2)[bA4 ^ i];
            a[2*i]   = make_float2(v.x, v.y);
            a[2*i+1] = make_float2(v.z, v.w);
        }

        // finalize readouts + head (overlaps next step's phase-A gates)
        if (tid < NQ) {
            float s = 0.f;
            #pragma unroll
            for (int w2 = 0; w2 < 16; ++w2) s += s_red[w2][tid];
            readouts[(k * BB + b) * NQ + tid] = s;
        }
        if (tid < 8) {
            float acc2 = s_hb[tid];
            #pragma unroll
            for (int i = 0; i < NQ; ++i) {
                float si = 0.f;
                #pragma unroll
                for (int w2 = 0; w2 < 16; ++w2) si += s_red[w2][i];
                acc2 = fmaf(si, s_hw[tid * NQ + i], acc2);
            }
            logits[(k * BB + b) * 8 + tid] = acc2;
            if (k == KS - 1) last[b * 8 + tid] = acc2;
        }
    }
}

extern "C" void kernel_launch(void* const* d_in, const int* in_sizes, int n_in,
                              void* d_out, int out_size, void* d_ws, size_t ws_size,
                              hipStream_t stream) {
    const int*   ids   = (const int*)d_in[0];
    const int*   mask  = (const int*)d_in[1];
    const float* emb   = (const float*)d_in[2];
    const float* pw    = (const float*)d_in[3];
    const float* pb    = (const float*)d_in[4];
    const float* theta = (const float*)d_in[5];
    const float* hw    = (const float*)d_in[6];
    const float* hb    = (const float*)d_in[7];
    float* out = (float*)d_out;

    float* readouts = out + KS * BB * 8;              // [K,B,NQ]
    float* last     = out + KS * BB * 8 + KS * BB * NQ;

    fused_kernel<<<BB, 1024, 0, stream>>>(ids, mask, emb, pw, pb, theta,
                                          hw, hb, readouts, out, last);
}

// Round 3
// 141.728 us; speedup vs baseline: 1.0341x; 1.0341x over previous
//
#include <hip/hip_runtime.h>
#include <math.h>

#define NQ 12
#define DIM 4096
#define KS 6
#define BB 256
#define SEQ 128
#define DEMB 512

// v4: back to 512 threads / 8 amps (the only config that hit 139.9 in the
// harness), with v3's harness-verified micro-opts grafted in:
//  - trips 1-2 (intra-wave) now __shfl_xor reg<->lane bit swaps (no LDS,
//    no lgkmcnt(0) drains; v1 spent 2 full drains + ~28 ds-ops/thread here)
//  - SU(2)-compressed gate precompute (4 independent reals per U)
// Cross-wave trips unchanged from v1 (verified): trip3 C->D (buf0, B1),
// trip4 ring scatter (buf1, B2). Expvals pre-ring in L_D, v1-verbatim.
//
// Layouts (j = 12-bit state index, wire w <-> bit 11-w):
//  L_A: r=j[2:0]  lane=j[8:3]            wave=j[11:9]
//  L_B: r=j[5:3]  lane={j[2:0],j[8:6]}   wave=j[11:9]
//  L_C: r=j[8:6]  lane=j[5:0]            wave=j[11:9]
//  L_D: r=j[11:9] lane=j[5:0]            wave=j[8:6]
// A->B: swap (r0,l0)(r1,l1)(r2,l2)  [j0<->j3, j1<->j4, j2<->j5]
// B->C: swap (r0,l3)(r1,l4)(r2,l5)  [j3<->j6, j4<->j7, j5<->j8]

#define RG(P, W) { \
    float4 c0 = *(const float4*)&s_u[k][W][0]; \
    float4 c1 = *(const float4*)&s_u[k][W][4]; \
    float u00r=c0.x,u00i=c0.y,u01r=c0.z,u01i=c0.w; \
    float u10r=c1.x,u10i=c1.y,u11r=c1.z,u11i=c1.w; \
    _Pragma("unroll") \
    for (int r0 = 0; r0 < 8; ++r0) if (!(r0 & (1 << (P)))) { \
        int r1 = r0 | (1 << (P)); \
        float2 A = a[r0], Bv = a[r1]; \
        a[r0].x = u00r*A.x - u00i*A.y + u01r*Bv.x - u01i*Bv.y; \
        a[r0].y = u00r*A.y + u00i*A.x + u01r*Bv.y + u01i*Bv.x; \
        a[r1].x = u10r*A.x - u10i*A.y + u11r*Bv.x - u11i*Bv.y; \
        a[r1].y = u10r*A.y + u10i*A.x + u11r*Bv.y + u11i*Bv.x; \
    } }

// Swap reg-bit (lo/hi pair) with lane-bit M: (r=1,lM=0) <-> (r=0,lM=1).
// Harness-verified in v3.
#define SWAPB(lo, hi, M) { \
    float tx_ = (lane & M) ? lo.x : hi.x; \
    float ty_ = (lane & M) ? lo.y : hi.y; \
    tx_ = __shfl_xor(tx_, M, 64); \
    ty_ = __shfl_xor(ty_, M, 64); \
    if (lane & M) { lo.x = tx_; lo.y = ty_; } \
    else          { hi.x = tx_; hi.y = ty_; } \
}

#define BF_PLAIN(v, m) { float p_ = __shfl_xor(v, m, 64); v = v + p_; }
#define BF_SIGN(v, m)  { float p_ = __shfl_xor(v, m, 64); float d_ = v - p_; \
                         v = (lane & m) ? -d_ : d_; }

__device__ __forceinline__ int swz14(int x) { return x ^ ((x >> 4) & 14); }

__global__ __launch_bounds__(512) void fused_kernel(
    const int* __restrict__ ids, const int* __restrict__ mask,
    const float* __restrict__ emb, const float* __restrict__ pw,
    const float* __restrict__ pb, const float* __restrict__ theta,
    const float* __restrict__ hw, const float* __restrict__ hb,
    float* __restrict__ readouts, float* __restrict__ logits,
    float* __restrict__ last)
{
    __shared__ __align__(16) float2 buf0[DIM];   // 32 KB (trip 3 / enc partials)
    __shared__ __align__(16) float2 buf1[DIM];   // 32 KB (ring scatter / enc ids)
    __shared__ __align__(16) float  s_u[KS][NQ][8];
    __shared__ float  s_red[8][NQ];
    __shared__ float  s_msum[4];
    __shared__ float  s_wred[2][NQ];
    __shared__ float  s_x[NQ];
    __shared__ float  s_hw[8 * NQ];
    __shared__ float  s_hb[8];

    int b = blockIdx.x;
    int tid = threadIdx.x;
    int lane = tid & 63, wave = tid >> 6;     // wave 0..7

    // ---------------- encoder (v1 verbatim) ----------------
    int*   s_ids = (int*)buf1;
    float* s_m   = (float*)buf1 + SEQ;
    float4* s_part = (float4*)buf0;           // [4][128]

    if (tid < SEQ) {
        s_ids[tid] = ids[b * SEQ + tid];
        s_m[tid]   = (float)mask[b * SEQ + tid];
    }
    if (tid >= 256 && tid < 256 + 8 * NQ) s_hw[tid - 256] = hw[tid - 256];
    if (tid >= 384 && tid < 392)          s_hb[tid - 384] = hb[tid - 384];
    __syncthreads();

    {
        int g = tid >> 7, e = tid & 127;
        float4 acc = make_float4(0.f, 0.f, 0.f, 0.f);
        float msum = 0.f;
        #pragma unroll 4
        for (int s = g; s < SEQ; s += 4) {
            float m = s_m[s];
            float4 v = ((const float4*)emb)[(size_t)s_ids[s] * 128 + e];
            acc.x = fmaf(m, v.x, acc.x);
            acc.y = fmaf(m, v.y, acc.y);
            acc.z = fmaf(m, v.z, acc.z);
            acc.w = fmaf(m, v.w, acc.w);
            msum += m;
        }
        __syncthreads();   // ids/m reads done before buf0 overlay write
        s_part[g * 128 + e] = acc;
        if (e == 0) s_msum[g] = msum;
    }
    __syncthreads();

    if (tid < 128) {
        float tm = fmaxf(s_msum[0] + s_msum[1] + s_msum[2] + s_msum[3], 1.f);
        float inv = 1.f / tm;
        float4 p0 = s_part[0 * 128 + tid], p1 = s_part[1 * 128 + tid];
        float4 p2 = s_part[2 * 128 + tid], p3 = s_part[3 * 128 + tid];
        float4 p;
        p.x = (p0.x + p1.x + p2.x + p3.x) * inv;
        p.y = (p0.y + p1.y + p2.y + p3.y) * inv;
        p.z = (p0.z + p1.z + p2.z + p3.z) * inv;
        p.w = (p0.w + p1.w + p2.w + p3.w) * inv;
        float z[NQ];
        #pragma unroll
        for (int i = 0; i < NQ; ++i) {
            float4 w4 = ((const float4*)pw)[i * 128 + tid];
            z[i] = p.x * w4.x + p.y * w4.y + p.z * w4.z + p.w * w4.w;
        }
        #pragma unroll
        for (int i = 0; i < NQ; ++i) {
            #pragma unroll
            for (int off = 32; off > 0; off >>= 1)
                z[i] += __shfl_xor(z[i], off, 64);
        }
        if ((tid & 63) == 0) {
            int w = tid >> 6;
            #pragma unroll
            for (int i = 0; i < NQ; ++i) s_wred[w][i] = z[i];
        }
    }
    __syncthreads();
    if (tid < NQ) {
        float d = pb[tid] + s_wred[0][tid] + s_wred[1][tid];
        s_x[tid] = tanhf(d) * 3.14159274101257324f;
    }
    __syncthreads();

    // ------ gate matrices: U = Rot(phi,te,om) @ RY(x), SU(2)-compressed ---
    // (harness-verified in R2) slots = [E0,E1,E2,E3,-E2,E3,E0,-E1]
    if (tid < KS * NQ * 4) {
        int k = tid / 48;
        int rem = tid - k * 48;
        int w = rem >> 2, q = rem & 3;
        float ang = s_x[w];
        float cy = cosf(0.5f * ang), sy = sinf(0.5f * ang);
        const float* th = theta + (k * NQ + w) * 3;
        float phi = th[0], te = th[1], om = th[2];
        float ct = cosf(0.5f * te), st = sinf(0.5f * te);
        float a1 = -0.5f * (phi + om);
        float a2 =  0.5f * (phi - om);
        float ar =  cosf(a1) * ct, ai =  sinf(a1) * ct;   // R00
        float br = -cosf(a2) * st, bi = -sinf(a2) * st;   // R01
        float x1 = (q & 1) ? ai : ar;
        float x2 = (q & 1) ? bi : br;
        float E  = (q & 2) ? (x2 * cy - x1 * sy) : (x1 * cy + x2 * sy);
        s_u[k][w][q] = E;
        s_u[k][w][(q & 2) ? q + 2 : q + 6] = (q == 1 || q == 2) ? -E : E;
    }

    // ---------------- constant addresses (cross-wave trips only) --------
    int T8 = tid << 3;
    int baseA  = swz14(T8);
    int baseA4 = baseA >> 1;          // float4 index; elem i at baseA4^i
    int addrC[8], addrD[8], idxP[8];
    #pragma unroll
    for (int r = 0; r < 8; ++r) {
        addrC[r] = swz14(lane + 64 * r + 512 * wave);
        int jD   = lane + 64 * wave + 512 * r;
        addrD[r] = swz14(jD);
        int b0 = (jD >> 11) & 1;
        int pref = b0, outv = 0;
        for (int w = 1; w < NQ; ++w) {
            pref ^= (jD >> (11 - w)) & 1;
            outv |= pref << (11 - w);
        }
        outv |= (b0 ^ pref) << 11;
        idxP[r] = swz14(outv);
    }
    int w0b = wave & 1, w1b = (wave >> 1) & 1, w2b = (wave >> 2) & 1;
    int wall = w0b ^ w1b ^ w2b;

    float2 a[8];
    #pragma unroll
    for (int r = 0; r < 8; ++r) a[r] = make_float2(0.f, 0.f);
    if (tid == 0) a[0].x = 1.f;
    __syncthreads();   // s_u ready, enc buf reads done

    // ---------------- K steps ----------------
    for (int k = 0; k < KS; ++k) {
        // phase 1 (L_A): wires 11,10,9
        RG(0, 11) RG(1, 10) RG(2, 9)

        // trip 1 (shuffle): swap (r0,l0)(r1,l1)(r2,l2)
        SWAPB(a[0], a[1], 1) SWAPB(a[2], a[3], 1)
        SWAPB(a[4], a[5], 1) SWAPB(a[6], a[7], 1)
        SWAPB(a[0], a[2], 2) SWAPB(a[1], a[3], 2)
        SWAPB(a[4], a[6], 2) SWAPB(a[5], a[7], 2)
        SWAPB(a[0], a[4], 4) SWAPB(a[1], a[5], 4)
        SWAPB(a[2], a[6], 4) SWAPB(a[3], a[7], 4)

        // phase 2 (L_B): wires 8,7,6
        RG(0, 8) RG(1, 7) RG(2, 6)

        // trip 2 (shuffle): swap (r0,l3)(r1,l4)(r2,l5)
        SWAPB(a[0], a[1], 8)  SWAPB(a[2], a[3], 8)
        SWAPB(a[4], a[5], 8)  SWAPB(a[6], a[7], 8)
        SWAPB(a[0], a[2], 16) SWAPB(a[1], a[3], 16)
        SWAPB(a[4], a[6], 16) SWAPB(a[5], a[7], 16)
        SWAPB(a[0], a[4], 32) SWAPB(a[1], a[5], 32)
        SWAPB(a[2], a[6], 32) SWAPB(a[3], a[7], 32)

        // phase 3 (L_C): wires 5,4,3
        RG(0, 5) RG(1, 4) RG(2, 3)

        // trip 3 (cross-wave): dump L_C -> barrier -> gather L_D
        #pragma unroll
        for (int r = 0; r < 8; ++r) buf0[addrC[r]] = a[r];
        __syncthreads();                                   // B1
        #pragma unroll
        for (int r = 0; r < 8; ++r) a[r] = buf0[addrD[r]];

        // phase 4 (L_D): wires 2,1,0
        RG(0, 2) RG(1, 1) RG(2, 0)

        // trip 4: issue ring scatter FIRST (drains while expvals shuffle)
        #pragma unroll
        for (int r = 0; r < 8; ++r) buf1[idxP[r]] = a[r];

        // expvals PRE-ring (L_D Walsh; v1-verbatim, verified)
        {
            float p[8];
            #pragma unroll
            for (int r = 0; r < 8; ++r)
                p[r] = a[r].x * a[r].x + a[r].y * a[r].y;
            float Q1 = (p[0]+p[1]+p[6]+p[7]) - (p[2]+p[3]+p[4]+p[5]);
            float Q2 = (p[0]+p[3]+p[5]+p[6]) - (p[1]+p[2]+p[4]+p[7]);
            float Q0 = (p[0]+p[3]+p[4]+p[7]) - (p[1]+p[2]+p[5]+p[6]);
            float q1 = Q1, q2p = Q2, q0 = Q0;
            BF_PLAIN(q1,32) BF_PLAIN(q1,16) BF_PLAIN(q1,8)
            BF_PLAIN(q1,4)  BF_PLAIN(q1,2)  BF_PLAIN(q1,1)
            BF_PLAIN(q2p,32) BF_PLAIN(q2p,16) BF_PLAIN(q2p,8)
            BF_PLAIN(q2p,4)  BF_PLAIN(q2p,2)  BF_PLAIN(q2p,1)
            BF_SIGN(q0,32) BF_SIGN(q0,16) BF_SIGN(q0,8)
            BF_SIGN(q0,4)  BF_SIGN(q0,2)  BF_SIGN(q0,1)
            float c = Q2;
            BF_SIGN(c,32);
            float w6v = c; BF_PLAIN(w6v,16) BF_PLAIN(w6v,8) BF_PLAIN(w6v,4)
                           BF_PLAIN(w6v,2)  BF_PLAIN(w6v,1)
            BF_SIGN(c,16);
            float w7v = c; BF_PLAIN(w7v,8) BF_PLAIN(w7v,4)
                           BF_PLAIN(w7v,2) BF_PLAIN(w7v,1)
            BF_SIGN(c,8);
            float w8v = c; BF_PLAIN(w8v,4) BF_PLAIN(w8v,2) BF_PLAIN(w8v,1)
            BF_SIGN(c,4);
            float w9v = c; BF_PLAIN(w9v,2) BF_PLAIN(w9v,1)
            BF_SIGN(c,2);
            float w10v = c; BF_PLAIN(w10v,1)
            BF_SIGN(c,1);
            if (lane == 0) {
                float* sr = s_red[wave];
                sr[0]  = wall ? -q0  : q0;
                sr[1]  = q1;
                sr[2]  = q2p;
                sr[3]  = w2b ? -q2p : q2p;
                sr[4]  = (w1b ^ w2b) ? -q2p : q2p;
                sr[5]  = wall ? -q2p : q2p;
                sr[6]  = wall ? -w6v : w6v;
                sr[7]  = wall ? -w7v : w7v;
                sr[8]  = wall ? -w8v : w8v;
                sr[9]  = wall ? -w9v : w9v;
                sr[10] = wall ? -w10v : w10v;
                sr[11] = wall ? -c   : c;
            }
        }

        __syncthreads();                                   // B2
        #pragma unroll
        for (int i = 0; i < 4; ++i) {
            float4 v = ((float4*)buf1)[baseA4 ^ i];
            a[2*i]   = make_float2(v.x, v.y);
            a[2*i+1] = make_float2(v.z, v.w);
        }

        // finalize readouts + head (overlaps next step's phase-1 gates)
        if (tid < NQ) {
            float s = 0.f;
            #pragma unroll
            for (int w2 = 0; w2 < 8; ++w2) s += s_red[w2][tid];
            readouts[(k * BB + b) * NQ + tid] = s;
        }
        if (tid < 8) {
            float acc2 = s_hb[tid];
            #pragma unroll
            for (int i = 0; i < NQ; ++i) {
                float si = 0.f;
                #pragma unroll
                for (int w2 = 0; w2 < 8; ++w2) si += s_red[w2][i];
                acc2 = fmaf(si, s_hw[tid * NQ + i], acc2);
            }
            logits[(k * BB + b) * 8 + tid] = acc2;
            if (k == KS - 1) last[b * 8 + tid] = acc2;
        }
    }
}

extern "C" void kernel_launch(void* const* d_in, const int* in_sizes, int n_in,
                              void* d_out, int out_size, void* d_ws, size_t ws_size,
                              hipStream_t stream) {
    const int*   ids   = (const int*)d_in[0];
    const int*   mask  = (const int*)d_in[1];
    const float* emb   = (const float*)d_in[2];
    const float* pw    = (const float*)d_in[3];
    const float* pb    = (const float*)d_in[4];
    const float* theta = (const float*)d_in[5];
    const float* hw    = (const float*)d_in[6];
    const float* hb    = (const float*)d_in[7];
    float* out = (float*)d_out;

    float* readouts = out + KS * BB * 8;              // [K,B,NQ]
    float* last     = out + KS * BB * 8 + KS * BB * NQ;

    fused_kernel<<<BB, 512, 0, stream>>>(ids, mask, emb, pw, pb, theta,
                                         hw, hb, readouts, out, last);
}

// Round 4
// 130.504 us; speedup vs baseline: 1.1230x; 1.0860x over previous
//
#include <hip/hip_runtime.h>
#include <math.h>

#define NQ 12
#define DIM 4096
#define KS 6
#define BB 256
#define SEQ 128
#define DEMB 512

// v5: v1 structure verbatim (512 threads / 8 amps, LDS trips, 2 barriers/step
// -- the best harness config, 139.9) with packed-FP32 gates:
//  - state held as <2 x float> (f2); each RG pair = 8 v_pk_fma_f32 instead of
//    16 scalar v_fma_f32 (VOP3P neg/op_sel folds the complex swap/sign)
//  - SU(2) compression: U = [[E0+iE1, E2+iE3],[-E2+iE3, E0-iE1]] -> only 4
//    reals per gate; row1 = PR0*B - PI0*Bs - PR1*A + PI1*As (verified algebra)
// R3 post-mortem: shuffle trips REGRESSED at 512t (75.4->81.3; shfl is a
// DS-pipe bpermute + selects) -> LDS trips restored. Bank conflicts (987K)
// cost only ~1.6us -- benign. Biggest remaining consumer = gate VALU issue
// (~24us of 75): halve it with pk math.
//
// Layouts (j = 12-bit state index, wire w <-> bit 11-w):
//   L_A: reg=bits0-2 (wires 11,10,9), lane=3-8, wave=9-11
//   L_B: reg=3-5 (8,7,6), lane=(0,1,2,6,7,8), wave=9-11
//   L_C: reg=6-8 (5,4,3), lane=0-5, wave=9-11
//   L_D: reg=9-11 (2,1,0), lane=0-5, wave=6-8
// Trips 1-2 intra-wave (buf0 + lgkmcnt fence); trip 3 cross-wave (B1);
// trip 4 = ring-folded scatter (buf1, B2). Expvals pre-ring via Walsh.

typedef float f2 __attribute__((ext_vector_type(2)));

#define RG(P, W) { \
    f2 E01 = *(const f2*)&s_u[k][W][0]; \
    f2 E23 = *(const f2*)&s_u[k][W][2]; \
    f2 PR0 = (f2){ E01.x,  E01.x}; \
    f2 PI0 = (f2){-E01.y,  E01.y}; \
    f2 PR1 = (f2){ E23.x,  E23.x}; \
    f2 PI1 = (f2){-E23.y,  E23.y}; \
    _Pragma("unroll") \
    for (int r0 = 0; r0 < 8; ++r0) if (!(r0 & (1 << (P)))) { \
        int r1 = r0 | (1 << (P)); \
        f2 A = a[r0], Bv = a[r1]; \
        f2 As = (f2){A.y, A.x}, Bs = (f2){Bv.y, Bv.x}; \
        a[r0] = PR0*A  + PI0*As + PR1*Bv + PI1*Bs; \
        a[r1] = PR0*Bv - PI0*Bs - PR1*A  + PI1*As; \
    } }

#define BF_PLAIN(v, m) { float p_ = __shfl_xor(v, m, 64); v = v + p_; }
#define BF_SIGN(v, m)  { float p_ = __shfl_xor(v, m, 64); float d_ = v - p_; \
                         v = (lane & m) ? -d_ : d_; }

// wave-local LDS write->read ordering (no block barrier)
#define WAVE_FENCE() asm volatile("s_waitcnt lgkmcnt(0)" ::: "memory")

__device__ __forceinline__ int swz14(int x) { return x ^ ((x >> 4) & 14); }

__global__ __launch_bounds__(512) void fused_kernel(
    const int* __restrict__ ids, const int* __restrict__ mask,
    const float* __restrict__ emb, const float* __restrict__ pw,
    const float* __restrict__ pb, const float* __restrict__ theta,
    const float* __restrict__ hw, const float* __restrict__ hb,
    float* __restrict__ readouts, float* __restrict__ logits,
    float* __restrict__ last)
{
    __shared__ __align__(16) f2    buf0[DIM];   // 32 KB (trips 1-3)
    __shared__ __align__(16) f2    buf1[DIM];   // 32 KB (trip 4 / enc)
    __shared__ __align__(16) float s_u[KS][NQ][4];
    __shared__ float  s_red[8][NQ];
    __shared__ float  s_msum[4];
    __shared__ float  s_wred[2][NQ];
    __shared__ float  s_x[NQ];
    __shared__ float  s_hw[8 * NQ];
    __shared__ float  s_hb[8];

    int b = blockIdx.x;
    int tid = threadIdx.x;
    int lane = tid & 63, wave = tid >> 6;     // wave 0..7

    // ---------------- encoder (v1 verbatim) ----------------
    int*   s_ids = (int*)buf1;
    float* s_m   = (float*)buf1 + SEQ;
    float4* s_part = (float4*)buf0;           // [4][128]

    if (tid < SEQ) {
        s_ids[tid] = ids[b * SEQ + tid];
        s_m[tid]   = (float)mask[b * SEQ + tid];
    }
    if (tid >= 256 && tid < 256 + 8 * NQ) s_hw[tid - 256] = hw[tid - 256];
    if (tid >= 384 && tid < 392)          s_hb[tid - 384] = hb[tid - 384];
    __syncthreads();

    {
        int g = tid >> 7, e = tid & 127;
        float4 acc = make_float4(0.f, 0.f, 0.f, 0.f);
        float msum = 0.f;
        #pragma unroll 4
        for (int s = g; s < SEQ; s += 4) {
            float m = s_m[s];
            float4 v = ((const float4*)emb)[(size_t)s_ids[s] * 128 + e];
            acc.x = fmaf(m, v.x, acc.x);
            acc.y = fmaf(m, v.y, acc.y);
            acc.z = fmaf(m, v.z, acc.z);
            acc.w = fmaf(m, v.w, acc.w);
            msum += m;
        }
        __syncthreads();   // ids/m reads done before buf0 overlay write
        s_part[g * 128 + e] = acc;
        if (e == 0) s_msum[g] = msum;
    }
    __syncthreads();

    if (tid < 128) {
        float tm = fmaxf(s_msum[0] + s_msum[1] + s_msum[2] + s_msum[3], 1.f);
        float inv = 1.f / tm;
        float4 p0 = s_part[0 * 128 + tid], p1 = s_part[1 * 128 + tid];
        float4 p2 = s_part[2 * 128 + tid], p3 = s_part[3 * 128 + tid];
        float4 p;
        p.x = (p0.x + p1.x + p2.x + p3.x) * inv;
        p.y = (p0.y + p1.y + p2.y + p3.y) * inv;
        p.z = (p0.z + p1.z + p2.z + p3.z) * inv;
        p.w = (p0.w + p1.w + p2.w + p3.w) * inv;
        float z[NQ];
        #pragma unroll
        for (int i = 0; i < NQ; ++i) {
            float4 w4 = ((const float4*)pw)[i * 128 + tid];
            z[i] = p.x * w4.x + p.y * w4.y + p.z * w4.z + p.w * w4.w;
        }
        #pragma unroll
        for (int i = 0; i < NQ; ++i) {
            #pragma unroll
            for (int off = 32; off > 0; off >>= 1)
                z[i] += __shfl_xor(z[i], off, 64);
        }
        if ((tid & 63) == 0) {
            int w = tid >> 6;
            #pragma unroll
            for (int i = 0; i < NQ; ++i) s_wred[w][i] = z[i];
        }
    }
    __syncthreads();
    if (tid < NQ) {
        float d = pb[tid] + s_wred[0][tid] + s_wred[1][tid];
        s_x[tid] = tanhf(d) * 3.14159274101257324f;
    }
    __syncthreads();

    // ------ gate matrices: U = Rot(phi,te,om) @ RY(x), SU(2)-compressed ---
    // (harness-verified R2/R3) E0..E3; U = [[E0+iE1, E2+iE3],[-E2+iE3, E0-iE1]]
    if (tid < KS * NQ * 4) {
        int k = tid / 48;
        int rem = tid - k * 48;
        int w = rem >> 2, q = rem & 3;
        float ang = s_x[w];
        float cy = cosf(0.5f * ang), sy = sinf(0.5f * ang);
        const float* th = theta + (k * NQ + w) * 3;
        float phi = th[0], te = th[1], om = th[2];
        float ct = cosf(0.5f * te), st = sinf(0.5f * te);
        float a1 = -0.5f * (phi + om);
        float a2 =  0.5f * (phi - om);
        float ar =  cosf(a1) * ct, ai =  sinf(a1) * ct;   // R00
        float br = -cosf(a2) * st, bi = -sinf(a2) * st;   // R01
        float x1 = (q & 1) ? ai : ar;
        float x2 = (q & 1) ? bi : br;
        float E  = (q & 2) ? (x2 * cy - x1 * sy) : (x1 * cy + x2 * sy);
        s_u[k][w][q] = E;
    }

    // ---------------- constant addresses ----------------
    int T8 = tid << 3;
    int baseA  = swz14(T8);
    int baseA4 = baseA >> 1;          // float4 index; elem i at baseA4^i
    int addrB[8], addrC[8], addrD[8], idxP[8];
    #pragma unroll
    for (int r = 0; r < 8; ++r) {
        addrB[r] = swz14((lane & 7) + 8 * r + 64 * (lane >> 3) + 512 * wave);
        addrC[r] = swz14(lane + 64 * r + 512 * wave);
        int jD   = lane + 64 * wave + 512 * r;
        addrD[r] = swz14(jD);
        int b0 = (jD >> 11) & 1;
        int pref = b0, outv = 0;
        for (int w = 1; w < NQ; ++w) {
            pref ^= (jD >> (11 - w)) & 1;
            outv |= pref << (11 - w);
        }
        outv |= (b0 ^ pref) << 11;
        idxP[r] = swz14(outv);
    }
    int w0b = wave & 1, w1b = (wave >> 1) & 1, w2b = (wave >> 2) & 1;
    int wall = w0b ^ w1b ^ w2b;

    f2 a[8];
    #pragma unroll
    for (int r = 0; r < 8; ++r) a[r] = (f2){0.f, 0.f};
    if (tid == 0) a[0].x = 1.f;
    __syncthreads();   // s_u ready, enc buf reads done

    // ---------------- K steps ----------------
    for (int k = 0; k < KS; ++k) {
        // phase 1 (L_A): wires 11,10,9
        RG(0, 11) RG(1, 10) RG(2, 9)

        // trip 1 (intra-wave): b128 dump -> gather L_B
        #pragma unroll
        for (int i = 0; i < 4; ++i)
            ((float4*)buf0)[baseA4 ^ i] =
                make_float4(a[2*i].x, a[2*i].y, a[2*i+1].x, a[2*i+1].y);
        WAVE_FENCE();
        #pragma unroll
        for (int r = 0; r < 8; ++r) a[r] = buf0[addrB[r]];

        // phase 2 (L_B): wires 8,7,6
        RG(0, 8) RG(1, 7) RG(2, 6)

        // trip 2 (intra-wave): dump L_B -> gather L_C
        #pragma unroll
        for (int r = 0; r < 8; ++r) buf0[addrB[r]] = a[r];
        WAVE_FENCE();
        #pragma unroll
        for (int r = 0; r < 8; ++r) a[r] = buf0[addrC[r]];

        // phase 3 (L_C): wires 5,4,3
        RG(0, 5) RG(1, 4) RG(2, 3)

        // trip 3 (cross-wave): dump L_C -> barrier -> gather L_D
        #pragma unroll
        for (int r = 0; r < 8; ++r) buf0[addrC[r]] = a[r];
        __syncthreads();                                   // B1
        #pragma unroll
        for (int r = 0; r < 8; ++r) a[r] = buf0[addrD[r]];

        // phase 4 (L_D): wires 2,1,0
        RG(0, 2) RG(1, 1) RG(2, 0)

        // trip 4: issue ring scatter FIRST (drains while expvals shuffle)
        #pragma unroll
        for (int r = 0; r < 8; ++r) buf1[idxP[r]] = a[r];

        // expvals PRE-ring (L_D Walsh; v1-verbatim, verified)
        {
            float p[8];
            #pragma unroll
            for (int r = 0; r < 8; ++r)
                p[r] = a[r].x * a[r].x + a[r].y * a[r].y;
            float Q1 = (p[0]+p[1]+p[6]+p[7]) - (p[2]+p[3]+p[4]+p[5]);
            float Q2 = (p[0]+p[3]+p[5]+p[6]) - (p[1]+p[2]+p[4]+p[7]);
            float Q0 = (p[0]+p[3]+p[4]+p[7]) - (p[1]+p[2]+p[5]+p[6]);
            float q1 = Q1, q2p = Q2, q0 = Q0;
            BF_PLAIN(q1,32) BF_PLAIN(q1,16) BF_PLAIN(q1,8)
            BF_PLAIN(q1,4)  BF_PLAIN(q1,2)  BF_PLAIN(q1,1)
            BF_PLAIN(q2p,32) BF_PLAIN(q2p,16) BF_PLAIN(q2p,8)
            BF_PLAIN(q2p,4)  BF_PLAIN(q2p,2)  BF_PLAIN(q2p,1)
            BF_SIGN(q0,32) BF_SIGN(q0,16) BF_SIGN(q0,8)
            BF_SIGN(q0,4)  BF_SIGN(q0,2)  BF_SIGN(q0,1)
            float c = Q2;
            BF_SIGN(c,32);
            float w6v = c; BF_PLAIN(w6v,16) BF_PLAIN(w6v,8) BF_PLAIN(w6v,4)
                           BF_PLAIN(w6v,2)  BF_PLAIN(w6v,1)
            BF_SIGN(c,16);
            float w7v = c; BF_PLAIN(w7v,8) BF_PLAIN(w7v,4)
                           BF_PLAIN(w7v,2) BF_PLAIN(w7v,1)
            BF_SIGN(c,8);
            float w8v = c; BF_PLAIN(w8v,4) BF_PLAIN(w8v,2) BF_PLAIN(w8v,1)
            BF_SIGN(c,4);
            float w9v = c; BF_PLAIN(w9v,2) BF_PLAIN(w9v,1)
            BF_SIGN(c,2);
            float w10v = c; BF_PLAIN(w10v,1)
            BF_SIGN(c,1);
            if (lane == 0) {
                float* sr = s_red[wave];
                sr[0]  = wall ? -q0  : q0;
                sr[1]  = q1;
                sr[2]  = q2p;
                sr[3]  = w2b ? -q2p : q2p;
                sr[4]  = (w1b ^ w2b) ? -q2p : q2p;
                sr[5]  = wall ? -q2p : q2p;
                sr[6]  = wall ? -w6v : w6v;
                sr[7]  = wall ? -w7v : w7v;
                sr[8]  = wall ? -w8v : w8v;
                sr[9]  = wall ? -w9v : w9v;
                sr[10] = wall ? -w10v : w10v;
                sr[11] = wall ? -c   : c;
            }
        }

        __syncthreads();                                   // B2
        #pragma unroll
        for (int i = 0; i < 4; ++i) {
            float4 v = ((float4*)buf1)[baseA4 ^ i];
            a[2*i]   = (f2){v.x, v.y};
            a[2*i+1] = (f2){v.z, v.w};
        }

        // finalize readouts + head (overlaps next step's phase-1 gates)
        if (tid < NQ) {
            float s = 0.f;
            #pragma unroll
            for (int w2 = 0; w2 < 8; ++w2) s += s_red[w2][tid];
            readouts[(k * BB + b) * NQ + tid] = s;
        }
        if (tid < 8) {
            float acc2 = s_hb[tid];
            #pragma unroll
            for (int i = 0; i < NQ; ++i) {
                float si = 0.f;
                #pragma unroll
                for (int w2 = 0; w2 < 8; ++w2) si += s_red[w2][i];
                acc2 = fmaf(si, s_hw[tid * NQ + i], acc2);
            }
            logits[(k * BB + b) * 8 + tid] = acc2;
            if (k == KS - 1) last[b * 8 + tid] = acc2;
        }
    }
}

extern "C" void kernel_launch(void* const* d_in, const int* in_sizes, int n_in,
                              void* d_out, int out_size, void* d_ws, size_t ws_size,
                              hipStream_t stream) {
    const int*   ids   = (const int*)d_in[0];
    const int*   mask  = (const int*)d_in[1];
    const float* emb   = (const float*)d_in[2];
    const float* pw    = (const float*)d_in[3];
    const float* pb    = (const float*)d_in[4];
    const float* theta = (const float*)d_in[5];
    const float* hw    = (const float*)d_in[6];
    const float* hb    = (const float*)d_in[7];
    float* out = (float*)d_out;

    float* readouts = out + KS * BB * 8;              // [K,B,NQ]
    float* last     = out + KS * BB * 8 + KS * BB * NQ;

    fused_kernel<<<BB, 512, 0, stream>>>(ids, mask, emb, pw, pb, theta,
                                         hw, hb, readouts, out, last);
}